// Round 8
// baseline (412.820 us; speedup 1.0000x reference)
//
#include <hip/hip_runtime.h>
#include <hip/hip_bf16.h>

#define CC 16
#define BB 16384
#define DD 256
#define NT 256
#define SLAB ((size_t)BB * DD)

typedef float f32x4 __attribute__((ext_vector_type(4)));
typedef short bf16x8 __attribute__((ext_vector_type(8)));
typedef short bf16x4 __attribute__((ext_vector_type(4)));

static __device__ __forceinline__ short bfc(float f) {
    return (short)__builtin_bit_cast(unsigned short, __float2bfloat16(f));
}
static __device__ __forceinline__ bf16x8 pack8(f32x4 a, f32x4 b) {
    bf16x8 v;
    v[0] = bfc(a[0]); v[1] = bfc(a[1]); v[2] = bfc(a[2]); v[3] = bfc(a[3]);
    v[4] = bfc(b[0]); v[5] = bfc(b[1]); v[6] = bfc(b[2]); v[7] = bfc(b[3]);
    return v;
}
static __device__ __forceinline__ float sigm(float x) {
    return __builtin_amdgcn_rcpf(1.0f + __expf(-x));
}
static __device__ __forceinline__ float tanh_(float x) {
    return 2.0f * __builtin_amdgcn_rcpf(1.0f + __expf(-2.0f * x)) - 1.0f;
}

// ---- prep: pack Wf (rows 0..255) + Wiou (rows 256..1023) f32 -> bf16 row-major
__global__ void prep(const float* __restrict__ Wf, const float* __restrict__ Wiou,
                     short* __restrict__ ws) {
    const int row = blockIdx.x;          // 0..1023
    const int t   = threadIdx.x;         // 0..63
    const float* src = (row < 256) ? (Wf + (size_t)row * DD)
                                   : (Wiou + (size_t)(row - 256) * DD);
    f32x4 v = *(const f32x4*)(src + t * 4);
    bf16x4 o; o[0] = bfc(v[0]); o[1] = bfc(v[1]); o[2] = bfc(v[2]); o[3] = bfc(v[3]);
    *(bf16x4*)(ws + (size_t)row * DD + t * 4) = o;
}

// ---- main: WAVE-AUTONOMOUS TreeLSTM node update.
// No LDS, no barriers in the c-loop: each wave loads its own A-fragments of
// h directly from global (lane reads h[b0+(l&15)][kk*32+(l>>4)*8], 32B/lane,
// 128B lines fully consumed; 8 waves sharing a row-group re-read h via L1/L2).
// Full next-child register prefetch (16KB in flight/wave) -> issue never
// stops. Single __syncthreads at the end to assemble hidden_sum fragments.
__global__ __launch_bounds__(NT, 2) void treelstm(
    const float* __restrict__ cmem,   // [C][B][D]
    const float* __restrict__ chid,   // [C][B][D]
    const short* __restrict__ wpk,    // packed bf16: Wf rows 0..255, Wiou 256..1023
    const float* __restrict__ bfv,    // [D]
    const float* __restrict__ biou,   // [3D]
    float* __restrict__ out)          // [2][B][D]
{
    __shared__ float hsbuf[16][264];   // f32, padded row stride (conflict-light)

    const int tid  = threadIdx.x;
    const int lane = tid & 63;
    const int wid  = tid >> 6;     // 0..3
    const int l15  = lane & 15;
    const int l4   = lane >> 4;    // 0..3
    const int bx   = blockIdx.x;
    const int b0   = (bx >> 1) * 16;               // row-group base
    const int cbase = (bx & 1) * 128 + wid * 32;   // wave's 32 output cols

    // A-fragment source: row b0+l15, d-offset l4*8 (+ kk*32)
    const float* hA = chid + (size_t)(b0 + l15) * DD + l4 * 8;

    // ---- issue h(0) (16 x dwordx4 per lane, 16KB per wave)
    f32x4 hv[16];
#pragma unroll
    for (int kk = 0; kk < 8; ++kk) {
        hv[2 * kk]     = *(const f32x4*)(hA + kk * 32);
        hv[2 * kk + 1] = *(const f32x4*)(hA + kk * 32 + 4);
    }

    // Wf B-frags resident: 2 n-frags x 8 k = 64 VGPR
    bf16x8 wfr[2][8];
    float bfr[2];
#pragma unroll
    for (int n = 0; n < 2; ++n) {
        const short* wr = wpk + (size_t)(cbase + n * 16 + l15) * DD + l4 * 8;
#pragma unroll
        for (int k = 0; k < 8; ++k) wfr[n][k] = *(const bf16x8*)(wr + k * 32);
        bfr[n] = bfv[cbase + n * 16 + l15];
    }

    // cm in C-frag layout (rows l4*4+j, col cbase+n*16+l15)
    const float* cmp = cmem + (size_t)(b0 + l4 * 4) * DD + cbase + l15;
    float cmv[8];
#pragma unroll
    for (int n = 0; n < 2; ++n)
#pragma unroll
        for (int j = 0; j < 4; ++j) cmv[n * 4 + j] = cmp[j * DD + n * 16];

    float hs[16], nmv[8];
#pragma unroll
    for (int i = 0; i < 16; ++i) hs[i] = 0.f;
#pragma unroll
    for (int i = 0; i < 8; ++i) nmv[i] = 0.f;

    bf16x8 a[8];

#pragma unroll 1
    for (int c = 0; c < CC; ++c) {
        // ---- consume h(c): hidden_sum chunks (wave owns kk=2wid,2wid+1) + pack
#pragma unroll
        for (int kk = 0; kk < 8; ++kk) {
            if ((kk >> 1) == wid) {            // wave-uniform predicate
                const int half = (kk & 1) * 8;
#pragma unroll
                for (int i = 0; i < 4; ++i) {
                    hs[half + i]     += hv[2 * kk][i];
                    hs[half + 4 + i] += hv[2 * kk + 1][i];
                }
            }
            a[kk] = pack8(hv[2 * kk], hv[2 * kk + 1]);
        }

        // ---- issue h(c+1) into the freed f32 bank (flies across MFMA phase)
        if (c + 1 < CC) {
            const float* hn = hA + (size_t)(c + 1) * SLAB;
#pragma unroll
            for (int kk = 0; kk < 8; ++kk) {
                hv[2 * kk]     = *(const f32x4*)(hn + kk * 32);
                hv[2 * kk + 1] = *(const f32x4*)(hn + kk * 32 + 4);
            }
        }
        // ---- issue cm(c+1)
        float cmn[8];
        if (c + 1 < CC) {
            const float* cn = cmp + (size_t)(c + 1) * SLAB;
#pragma unroll
            for (int n = 0; n < 2; ++n)
#pragma unroll
                for (int j = 0; j < 4; ++j) cmn[n * 4 + j] = cn[j * DD + n * 16];
        }

        // ---- forget-gate GEMM: 16 MFMA, no LDS
        f32x4 acc0 = {bfr[0], bfr[0], bfr[0], bfr[0]};
        f32x4 acc1 = {bfr[1], bfr[1], bfr[1], bfr[1]};
#pragma unroll
        for (int kk = 0; kk < 8; ++kk) {
            acc0 = __builtin_amdgcn_mfma_f32_16x16x32_bf16(a[kk], wfr[0][kk], acc0, 0, 0, 0);
            acc1 = __builtin_amdgcn_mfma_f32_16x16x32_bf16(a[kk], wfr[1][kk], acc1, 0, 0, 0);
        }

        // ---- node_memory += sigmoid(fg) * cm
#pragma unroll
        for (int j = 0; j < 4; ++j) {
            nmv[j]     += sigm(acc0[j]) * cmv[j];
            nmv[4 + j] += sigm(acc1[j]) * cmv[4 + j];
        }
        if (c + 1 < CC) {
#pragma unroll
            for (int i = 0; i < 8; ++i) cmv[i] = cmn[i];
        }
    }

    // ---- hidden_sum exchange (single barrier in the whole kernel)
    {
        float* p0 = &hsbuf[l15][(2 * wid) * 32 + l4 * 8];
        f32x4 s0 = {hs[0], hs[1], hs[2], hs[3]};
        f32x4 s1 = {hs[4], hs[5], hs[6], hs[7]};
        f32x4 s2 = {hs[8], hs[9], hs[10], hs[11]};
        f32x4 s3 = {hs[12], hs[13], hs[14], hs[15]};
        *(f32x4*)(p0)      = s0;
        *(f32x4*)(p0 + 4)  = s1;
        *(f32x4*)(p0 + 32) = s2;
        *(f32x4*)(p0 + 36) = s3;
    }
    __syncthreads();

    bf16x8 afr[8];
#pragma unroll
    for (int kk = 0; kk < 8; ++kk) {
        f32x4 x0 = *(const f32x4*)(&hsbuf[l15][kk * 32 + l4 * 8]);
        f32x4 x1 = *(const f32x4*)(&hsbuf[l15][kk * 32 + l4 * 8 + 4]);
        afr[kk] = pack8(x0, x1);
    }

    // ---- iou GEMM from packed Wiou (streamed from L2)
    float gq[3][8];
#pragma unroll
    for (int q = 0; q < 3; ++q) {
#pragma unroll
        for (int n = 0; n < 2; ++n) {
            const short* wr = wpk + (size_t)(256 + q * 256 + cbase + n * 16 + l15) * DD + l4 * 8;
            f32x4 acc = {0.f, 0.f, 0.f, 0.f};
#pragma unroll
            for (int kk = 0; kk < 8; ++kk)
                acc = __builtin_amdgcn_mfma_f32_16x16x32_bf16(afr[kk], *(const bf16x8*)(wr + kk * 32), acc, 0, 0, 0);
            float bq = biou[q * 256 + cbase + n * 16 + l15];
#pragma unroll
            for (int j = 0; j < 4; ++j) gq[q][n * 4 + j] = acc[j] + bq;
        }
    }

    // ---- gates + stores
    float* o0p = out + (size_t)(b0 + l4 * 4) * DD + cbase + l15;
    float* o1p = o0p + SLAB;
#pragma unroll
    for (int n = 0; n < 2; ++n)
#pragma unroll
        for (int j = 0; j < 4; ++j) {
            float ig = sigm(gq[0][n * 4 + j]);
            float og = sigm(gq[1][n * 4 + j]);
            float ug = tanh_(gq[2][n * 4 + j]);
            float mm = nmv[n * 4 + j] + ig * ug;
            float hh = og * tanh_(mm);
            o0p[j * DD + n * 16] = mm;
            o1p[j * DD + n * 16] = hh;
        }
}

extern "C" void kernel_launch(void* const* d_in, const int* in_sizes, int n_in,
                              void* d_out, int out_size, void* d_ws, size_t ws_size,
                              hipStream_t stream) {
    const float* cmem = (const float*)d_in[0];
    const float* chid = (const float*)d_in[1];
    const float* Wf   = (const float*)d_in[2];
    const float* bf   = (const float*)d_in[3];
    const float* Wiou = (const float*)d_in[4];
    const float* biou = (const float*)d_in[5];
    float* out = (float*)d_out;
    short* wpk = (short*)d_ws;    // 1024 x 256 bf16 = 512 KiB

    prep<<<1024, 64, 0, stream>>>(Wf, Wiou, wpk);
    treelstm<<<(BB / 16) * 2, NT, 0, stream>>>(cmem, chid, wpk, bf, biou, out);
}

// Round 9
// 166.198 us; speedup vs baseline: 2.4839x; 2.4839x over previous
//
#include <hip/hip_runtime.h>
#include <hip/hip_bf16.h>

#define CC 16
#define BB 16384
#define DD 256
#define NT 512
#define SLAB ((size_t)BB * DD)

typedef float f32x4 __attribute__((ext_vector_type(4)));
typedef short bf16x8 __attribute__((ext_vector_type(8)));
typedef short bf16x4 __attribute__((ext_vector_type(4)));

static __device__ __forceinline__ short bfc(float f) {
    return (short)__builtin_bit_cast(unsigned short, __float2bfloat16(f));
}
static __device__ __forceinline__ bf16x8 pack8(f32x4 a, f32x4 b) {
    bf16x8 v;
    v[0] = bfc(a[0]); v[1] = bfc(a[1]); v[2] = bfc(a[2]); v[3] = bfc(a[3]);
    v[4] = bfc(b[0]); v[5] = bfc(b[1]); v[6] = bfc(b[2]); v[7] = bfc(b[3]);
    return v;
}
static __device__ __forceinline__ float sigm(float x) {
    return __builtin_amdgcn_rcpf(1.0f + __expf(-x));
}
static __device__ __forceinline__ float tanh_(float x) {
    return 2.0f * __builtin_amdgcn_rcpf(1.0f + __expf(-2.0f * x)) - 1.0f;
}

typedef __attribute__((address_space(3))) void lds_void;
typedef const __attribute__((address_space(1))) void gl_void;
static __device__ __forceinline__ void stage16(const void* g, void* l) {
    __builtin_amdgcn_global_load_lds((gl_void*)g, (lds_void*)l, 16, 0, 0);
}

// ---- prep: pack Wf (rows 0..255) + Wiou (rows 256..1023) f32 -> bf16
__global__ void prep(const float* __restrict__ Wf, const float* __restrict__ Wiou,
                     short* __restrict__ ws) {
    const int row = blockIdx.x;
    const int t   = threadIdx.x;
    const float* src = (row < 256) ? (Wf + (size_t)row * DD)
                                   : (Wiou + (size_t)(row - 256) * DD);
    f32x4 v = *(const f32x4*)(src + t * 4);
    bf16x4 o; o[0] = bfc(v[0]); o[1] = bfc(v[1]); o[2] = bfc(v[2]); o[3] = bfc(v[3]);
    *(bf16x4*)(ws + (size_t)row * DD + t * 4) = o;
}

// ---- main: TreeLSTM, deep-pipelined global_load_lds staging.
// 512 thr = 8 waves; block = 16 rows x 256 cols; wave owns 32 output cols.
// h staged as f32 via global_load_lds into a TRIPLE buffer (3 x 16KB), issued
// 2 children ahead; source pre-swizzled (phys granule = logical ^ row within
// 512B half-row), LDS dest linear, reads XOR-swizzled (R6 layout, 0-conflict).
// Every phase issues exactly 10 VMEM/wave (2 stage + 8 cm; tail clamps index)
// so a constant s_waitcnt vmcnt(18) + raw s_barrier per phase suffices —
// the pipe never drains. cm register loads are compiler-counted.
__global__ __launch_bounds__(NT, 2) void treelstm(
    const float* __restrict__ cmem,   // [C][B][D]
    const float* __restrict__ chid,   // [C][B][D]
    const short* __restrict__ wpk,    // bf16: Wf rows 0..255, Wiou 256..1023
    const float* __restrict__ bfv,    // [D]
    const float* __restrict__ biou,   // [3D]
    float* __restrict__ out)          // [2][B][D]
{
    __shared__ __align__(1024) unsigned char hb[3][16 * 1024];   // 48 KiB f32 tiles

    const int tid  = threadIdx.x;
    const int lane = tid & 63;
    const int wid  = tid >> 6;     // 0..7
    const int l15  = lane & 15;
    const int l4   = lane >> 4;    // 0..3
    const int b0   = blockIdx.x * 16;
    const int wc0  = wid * 32;

    // ---- weight fragments first (program-order pinned before staging)
    bf16x8 wfr[2][8];
    float bfr[2];
#pragma unroll
    for (int n = 0; n < 2; ++n) {
        const short* wr = wpk + (size_t)(wc0 + n * 16 + l15) * DD + l4 * 8;
#pragma unroll
        for (int k = 0; k < 8; ++k) wfr[n][k] = *(const bf16x8*)(wr + k * 32);
        bfr[n] = bfv[wc0 + n * 16 + l15];
    }
    __builtin_amdgcn_sched_barrier(0);

    // ---- staging geometry: wave stages rows r0=2wid, r1=2wid+1 (1 row/instr).
    // phys granule lane -> logical (lane&32)|((lane&31)^row)  (self-inverse)
    const int r0 = 2 * wid, r1 = r0 + 1;
    const int g0 = (lane & 32) | ((lane & 31) ^ r0);
    const int g1 = (lane & 32) | ((lane & 31) ^ r1);
    const float* hsrc0 = chid + (size_t)(b0 + r0) * DD + g0 * 4;
    const float* hsrc1 = chid + (size_t)(b0 + r1) * DD + g1 * 4;

    unsigned char* pc = &hb[0][0];   // holds h(c)
    unsigned char* pn = &hb[1][0];   // holds h(c+1)
    unsigned char* pf = &hb[2][0];   // staging target h(c+2)

    // ---- prologue: stage h(0)->buf0, h(1)->buf1; cm(0) -> regs
    stage16(hsrc0, pc + r0 * 1024);
    stage16(hsrc1, pc + r1 * 1024);
    stage16(hsrc0 + SLAB, pn + r0 * 1024);
    stage16(hsrc1 + SLAB, pn + r1 * 1024);

    const float* cmp = cmem + (size_t)(b0 + l4 * 4) * DD + wc0 + l15;
    float cmC[8];
#pragma unroll
    for (int n = 0; n < 2; ++n)
#pragma unroll
        for (int j = 0; j < 4; ++j) cmC[n * 4 + j] = cmp[j * DD + n * 16];

    __builtin_amdgcn_sched_barrier(0);
    asm volatile("s_waitcnt vmcnt(10)" ::: "memory");   // h(0) staged
    __builtin_amdgcn_s_barrier();
    __builtin_amdgcn_sched_barrier(0);

    float hs[8], nmv[8];
#pragma unroll
    for (int i = 0; i < 8; ++i) { hs[i] = 0.f; nmv[i] = 0.f; }

#pragma unroll 1
    for (int c = 0; c < CC; ++c) {
        const int hc = (c + 2 < CC) ? c + 2 : CC - 1;   // clamp keeps VMEM count uniform
        const int mc = (c + 1 < CC) ? c + 1 : CC - 1;

        // issue stage h(c+2) -> pf  (deadline: barrier of phase c+2)
        stage16(hsrc0 + (size_t)hc * SLAB, pf + r0 * 1024);
        stage16(hsrc1 + (size_t)hc * SLAB, pf + r1 * 1024);
        // issue cm(c+1) -> regs (deadline: nmv of phase c+1, compiler-counted)
        float cmN[8];
        {
            const float* cn = cmp + (size_t)mc * SLAB;
#pragma unroll
            for (int n = 0; n < 2; ++n)
#pragma unroll
                for (int j = 0; j < 4; ++j) cmN[n * 4 + j] = cn[j * DD + n * 16];
        }
        __builtin_amdgcn_sched_barrier(0);

        // ---- compute on h(c) from pc: 16 ds_read_b128 f32 -> pack -> 16 MFMA
        f32x4 acc0 = {bfr[0], bfr[0], bfr[0], bfr[0]};
        f32x4 acc1 = {bfr[1], bfr[1], bfr[1], bfr[1]};
        const unsigned char* bc = pc + l15 * 1024;
#pragma unroll
        for (int kk = 0; kk < 8; ++kk) {
            const int half = (kk >> 2) * 512;
            const int gl = (kk & 3) * 8 + l4 * 2;
            f32x4 x0 = *(const f32x4*)(bc + half + ((gl ^ l15) << 4));
            f32x4 x1 = *(const f32x4*)(bc + half + (((gl + 1) ^ l15) << 4));
            if (kk == wid) {     // wave-uniform: wave owns its hidden_sum chunk
#pragma unroll
                for (int i = 0; i < 4; ++i) { hs[i] += x0[i]; hs[4 + i] += x1[i]; }
            }
            bf16x8 a = pack8(x0, x1);
            acc0 = __builtin_amdgcn_mfma_f32_16x16x32_bf16(a, wfr[0][kk], acc0, 0, 0, 0);
            acc1 = __builtin_amdgcn_mfma_f32_16x16x32_bf16(a, wfr[1][kk], acc1, 0, 0, 0);
        }

        // ---- node_memory += sigmoid(fg) * cm(c)
#pragma unroll
        for (int j = 0; j < 4; ++j) {
            nmv[j]     += sigm(acc0[j]) * cmC[j];
            nmv[4 + j] += sigm(acc1[j]) * cmC[4 + j];
        }
#pragma unroll
        for (int i = 0; i < 8; ++i) cmC[i] = cmN[i];

        // rotate buffers
        unsigned char* t = pc; pc = pn; pn = pf; pf = t;

        // h(c+1) staged (18 newer VMEM: 8 cm of phase c-1 + 10 of phase c)
        asm volatile("s_waitcnt vmcnt(18)" ::: "memory");
        __builtin_amdgcn_s_barrier();
        __builtin_amdgcn_sched_barrier(0);
    }

    // ---- epilogue: hidden_sum -> hb[0] (all phases done; same swizzled layout)
    {
        unsigned char* wbuf = &hb[0][0];
        const int glo = (wid & 3) * 8 + l4 * 2;
        const int half = (wid >> 2) * 512;
        f32x4 s0 = {hs[0], hs[1], hs[2], hs[3]};
        f32x4 s1 = {hs[4], hs[5], hs[6], hs[7]};
        *(f32x4*)(wbuf + l15 * 1024 + half + ((glo ^ l15) << 4)) = s0;
        *(f32x4*)(wbuf + l15 * 1024 + half + (((glo + 1) ^ l15) << 4)) = s1;
    }
    asm volatile("s_waitcnt lgkmcnt(0)" ::: "memory");
    __builtin_amdgcn_s_barrier();
    __builtin_amdgcn_sched_barrier(0);

    bf16x8 afr[8];
    {
        const unsigned char* bc = &hb[0][0] + l15 * 1024;
#pragma unroll
        for (int kk = 0; kk < 8; ++kk) {
            const int half = (kk >> 2) * 512;
            const int gl = (kk & 3) * 8 + l4 * 2;
            f32x4 x0 = *(const f32x4*)(bc + half + ((gl ^ l15) << 4));
            f32x4 x1 = *(const f32x4*)(bc + half + (((gl + 1) ^ l15) << 4));
            afr[kk] = pack8(x0, x1);
        }
    }

    // ---- iou GEMM from packed Wiou
    float gq[3][8];
#pragma unroll
    for (int q = 0; q < 3; ++q) {
#pragma unroll
        for (int n = 0; n < 2; ++n) {
            const short* wr = wpk + (size_t)(256 + q * 256 + wc0 + n * 16 + l15) * DD + l4 * 8;
            f32x4 acc = {0.f, 0.f, 0.f, 0.f};
#pragma unroll
            for (int kk = 0; kk < 8; ++kk)
                acc = __builtin_amdgcn_mfma_f32_16x16x32_bf16(afr[kk], *(const bf16x8*)(wr + kk * 32), acc, 0, 0, 0);
            float bq = biou[q * 256 + wc0 + n * 16 + l15];
#pragma unroll
            for (int j = 0; j < 4; ++j) gq[q][n * 4 + j] = acc[j] + bq;
        }
    }

    // ---- gates + stores
    float* o0p = out + (size_t)(b0 + l4 * 4) * DD + wc0 + l15;
    float* o1p = o0p + SLAB;
#pragma unroll
    for (int n = 0; n < 2; ++n)
#pragma unroll
        for (int j = 0; j < 4; ++j) {
            float ig = sigm(gq[0][n * 4 + j]);
            float og = sigm(gq[1][n * 4 + j]);
            float ug = tanh_(gq[2][n * 4 + j]);
            float mm = nmv[n * 4 + j] + ig * ug;
            float hh = og * tanh_(mm);
            o0p[j * DD + n * 16] = mm;
            o1p[j * DD + n * 16] = hh;
        }
}

extern "C" void kernel_launch(void* const* d_in, const int* in_sizes, int n_in,
                              void* d_out, int out_size, void* d_ws, size_t ws_size,
                              hipStream_t stream) {
    const float* cmem = (const float*)d_in[0];
    const float* chid = (const float*)d_in[1];
    const float* Wf   = (const float*)d_in[2];
    const float* bf   = (const float*)d_in[3];
    const float* Wiou = (const float*)d_in[4];
    const float* biou = (const float*)d_in[5];
    float* out = (float*)d_out;
    short* wpk = (short*)d_ws;    // 1024 x 256 bf16 = 512 KiB

    prep<<<1024, 64, 0, stream>>>(Wf, Wiou, wpk);
    treelstm<<<BB / 16, NT, 0, stream>>>(cmem, chid, wpk, bf, biou, out);
}